// Round 2
// baseline (287.622 us; speedup 1.0000x reference)
//
#include <hip/hip_runtime.h>

using bf16x8 = __attribute__((ext_vector_type(8))) short;
using f32x4  = __attribute__((ext_vector_type(4))) float;
using u32x4  = __attribute__((ext_vector_type(4))) unsigned int;

__device__ __forceinline__ unsigned short f2bf(float f) {
  unsigned int u = __builtin_bit_cast(unsigned int, f);
  u += 0x7FFF + ((u >> 16) & 1);               // RNE
  return (unsigned short)(u >> 16);
}
__device__ __forceinline__ bf16x8 lds_frag(const unsigned short* p) {
  return __builtin_bit_cast(bf16x8, *(const u32x4*)p);
}

// fp32 -> bf16 elementwise, 8 elems/thread
__global__ void cast_bf16_k(const float* __restrict__ in,
                            unsigned short* __restrict__ out, int n) {
  int i = (blockIdx.x * 256 + threadIdx.x) * 8;
  if (i < n) {
    unsigned short r[8];
    #pragma unroll
    for (int j = 0; j < 8; ++j) r[j] = f2bf(in[i + j]);
    *(u32x4*)&out[i] = *(u32x4*)r;
  }
}

// out[c*R + r] = bf16(in[r*C + c])   (in: R x C fp32, out: C x R bf16)
__global__ void transpose_cast_k(const float* __restrict__ in,
                                 unsigned short* __restrict__ out, int R, int C) {
  int idx = blockIdx.x * 256 + threadIdx.x;
  if (idx < R * C) {
    int c = idx / R, r = idx - c * R;
    out[idx] = f2bf(in[r * C + c]);
  }
}

// C[M,N] = A[M,K] @ Bt[N,K]^T (+bias for fp32 out), A/Bt bf16, fp32 accum.
// 128x128 tile, BK=32, 4 waves in 2x2, 4x4 16x16x32 MFMA tiles per wave.
template <typename OutT>
__global__ __launch_bounds__(256, 2)
void gemm_bt(const unsigned short* __restrict__ A,
             const unsigned short* __restrict__ Bt,
             OutT* __restrict__ C,
             const float* __restrict__ bias,
             int M, int N, int K) {
  __shared__ unsigned short Ash[128 * 32];
  __shared__ unsigned short Bsh[128 * 32];
  const int tid  = threadIdx.x;
  const int wv   = tid >> 6, lane = tid & 63;
  const int quad = lane >> 4, l15 = lane & 15;
  const int wr   = wv >> 1, wc = wv & 1;
  const int m0 = blockIdx.y * 128, n0 = blockIdx.x * 128;

  f32x4 acc[4][4];
  #pragma unroll
  for (int i = 0; i < 4; ++i)
    #pragma unroll
    for (int j = 0; j < 4; ++j)
      acc[i][j] = (f32x4){0.f, 0.f, 0.f, 0.f};

  for (int k0 = 0; k0 < K; k0 += 32) {
    #pragma unroll
    for (int p = 0; p < 2; ++p) {
      int lin = p * 256 + tid;
      int row = lin >> 2, c8 = (lin & 3) << 3;
      *(u32x4*)&Ash[row * 32 + c8] = *(const u32x4*)&A[(size_t)(m0 + row) * K + k0 + c8];
      *(u32x4*)&Bsh[row * 32 + c8] = *(const u32x4*)&Bt[(size_t)(n0 + row) * K + k0 + c8];
    }
    __syncthreads();
    bf16x8 af[4], bfr[4];
    #pragma unroll
    for (int i = 0; i < 4; ++i)
      af[i] = lds_frag(&Ash[(wr * 64 + i * 16 + l15) * 32 + quad * 8]);
    #pragma unroll
    for (int j = 0; j < 4; ++j)
      bfr[j] = lds_frag(&Bsh[(wc * 64 + j * 16 + l15) * 32 + quad * 8]);
    #pragma unroll
    for (int i = 0; i < 4; ++i)
      #pragma unroll
      for (int j = 0; j < 4; ++j)
        acc[i][j] = __builtin_amdgcn_mfma_f32_16x16x32_bf16(af[i], bfr[j], acc[i][j], 0, 0, 0);
    __syncthreads();
  }

  #pragma unroll
  for (int i = 0; i < 4; ++i) {
    #pragma unroll
    for (int j = 0; j < 4; ++j) {
      int col = n0 + wc * 64 + j * 16 + l15;
      float badd = (bias != nullptr) ? bias[col] : 0.f;
      #pragma unroll
      for (int r = 0; r < 4; ++r) {
        int row = m0 + wr * 64 + i * 16 + quad * 4 + r;
        if constexpr (sizeof(OutT) == 2)
          C[(size_t)row * N + col] = f2bf(acc[i][j][r] + badd);
        else
          C[(size_t)row * N + col] = acc[i][j][r] + badd;
      }
    }
  }
}

// Local attention: one block per (head, window). qkv: 16384 x 1536 bf16,
// out: 16384 x 512 bf16. WSZ=128, lookback window of 128 (zeros for w==0).
// mask: col <= row + 128. scale = 1/8.
__global__ __launch_bounds__(256, 2)
void attn_local(const unsigned short* __restrict__ qkv,
                unsigned short* __restrict__ out) {
  // Ksh layout: [ks(2)][j(256)][32]  (32-col k-tiles -> b128 frag reads, 64B row stride)
  __shared__ unsigned short Ksh[2 * 256 * 32];   // 32 KB
  __shared__ unsigned short Vsh[256 * 64];       // 32 KB, row-major [k][n]
  unsigned short* Psh = Ksh;                     // P overlays K after scores

  const int tid  = threadIdx.x;
  const int wv   = tid >> 6, lane = tid & 63;
  const int quad = lane >> 4, l15 = lane & 15;
  const int h = blockIdx.x & 7, w = blockIdx.x >> 3;

  // stage K (tiled) and V (row-major); rows j<128 of window 0 are zeros
  #pragma unroll
  for (int p = 0; p < 8; ++p) {
    int c = p * 256 + tid;
    int j = c >> 3, sub = c & 7;
    u32x4 kvv = (u32x4){0, 0, 0, 0}, vvv = (u32x4){0, 0, 0, 0};
    if (!(w == 0 && j < 128)) {
      size_t base = (size_t)((w - 1) * 128 + j) * 1536 + h * 64 + sub * 8;
      kvv = *(const u32x4*)&qkv[base + 512];
      vvv = *(const u32x4*)&qkv[base + 1024];
    }
    *(u32x4*)&Ksh[(sub >> 2) * 8192 + j * 32 + (sub & 3) * 8] = kvv;
    *(u32x4*)&Vsh[j * 64 + sub * 8] = vvv;
  }
  __syncthreads();

  // Q fragments straight from global (A-operand layout: row l15, k = ks*32+quad*8..+7)
  bf16x8 qf[2][2];
  #pragma unroll
  for (int mt = 0; mt < 2; ++mt) {
    int tok = w * 128 + (wv * 2 + mt) * 16 + l15;
    #pragma unroll
    for (int ks = 0; ks < 2; ++ks)
      qf[mt][ks] = __builtin_bit_cast(
          bf16x8, *(const u32x4*)&qkv[(size_t)tok * 1536 + h * 64 + ks * 32 + quad * 8]);
  }

  // scores: wave wv owns rows [wv*32, wv*32+32) => m-tiles {2wv, 2wv+1}
  float s[2][16][4];
  #pragma unroll
  for (int nt = 0; nt < 16; ++nt) {
    bf16x8 kf0 = lds_frag(&Ksh[0    + (nt * 16 + l15) * 32 + quad * 8]);
    bf16x8 kf1 = lds_frag(&Ksh[8192 + (nt * 16 + l15) * 32 + quad * 8]);
    #pragma unroll
    for (int mt = 0; mt < 2; ++mt) {
      f32x4 a = (f32x4){0.f, 0.f, 0.f, 0.f};
      a = __builtin_amdgcn_mfma_f32_16x16x32_bf16(qf[mt][0], kf0, a, 0, 0, 0);
      a = __builtin_amdgcn_mfma_f32_16x16x32_bf16(qf[mt][1], kf1, a, 0, 0, 0);
      #pragma unroll
      for (int r = 0; r < 4; ++r) s[mt][nt][r] = a[r];
    }
  }

  // masked softmax in registers (row = mtile*16 + quad*4 + r, col = nt*16 + l15)
  #pragma unroll
  for (int mt = 0; mt < 2; ++mt) {
    int rowb = (wv * 2 + mt) * 16 + quad * 4;
    #pragma unroll
    for (int r = 0; r < 4; ++r) {
      int lim = rowb + r + 128;
      float mx = -3.0e38f;
      #pragma unroll
      for (int nt = 0; nt < 16; ++nt) {
        float v = ((nt * 16 + l15) <= lim) ? s[mt][nt][r] * 0.125f : -3.0e38f;
        s[mt][nt][r] = v;
        mx = fmaxf(mx, v);
      }
      mx = fmaxf(mx, __shfl_xor(mx, 1));
      mx = fmaxf(mx, __shfl_xor(mx, 2));
      mx = fmaxf(mx, __shfl_xor(mx, 4));
      mx = fmaxf(mx, __shfl_xor(mx, 8));
      float sum = 0.f;
      #pragma unroll
      for (int nt = 0; nt < 16; ++nt) {
        float p = __expf(s[mt][nt][r] - mx);   // masked -> exp(-huge) = 0
        s[mt][nt][r] = p;
        sum += p;
      }
      sum += __shfl_xor(sum, 1);
      sum += __shfl_xor(sum, 2);
      sum += __shfl_xor(sum, 4);
      sum += __shfl_xor(sum, 8);
      float inv = 1.f / sum;
      #pragma unroll
      for (int nt = 0; nt < 16; ++nt) s[mt][nt][r] *= inv;
    }
  }

  __syncthreads();   // all waves done reading Ksh -> safe to overlay P

  // PV: per m-tile, round-trip P through per-wave LDS region (C-layout -> A-layout)
  // P region layout per wave: [ks(8)][row(16)][32]  (64B row stride, b128-aligned)
  #pragma unroll
  for (int mt = 0; mt < 2; ++mt) {
    #pragma unroll
    for (int nt = 0; nt < 16; ++nt)
      #pragma unroll
      for (int r = 0; r < 4; ++r)
        Psh[wv * 4096 + (nt >> 1) * 512 + (quad * 4 + r) * 32 + (nt & 1) * 16 + l15] =
            f2bf(s[mt][nt][r]);
    __syncthreads();
    f32x4 o[4];
    #pragma unroll
    for (int n2 = 0; n2 < 4; ++n2) o[n2] = (f32x4){0.f, 0.f, 0.f, 0.f};
    #pragma unroll
    for (int ks = 0; ks < 8; ++ks) {
      bf16x8 pa = lds_frag(&Psh[wv * 4096 + ks * 512 + l15 * 32 + quad * 8]);
      #pragma unroll
      for (int n2 = 0; n2 < 4; ++n2) {
        bf16x8 vb;
        #pragma unroll
        for (int jj = 0; jj < 8; ++jj)
          vb[jj] = (short)Vsh[(ks * 32 + quad * 8 + jj) * 64 + n2 * 16 + l15];
        o[n2] = __builtin_amdgcn_mfma_f32_16x16x32_bf16(pa, vb, o[n2], 0, 0, 0);
      }
    }
    int tokb = w * 128 + (wv * 2 + mt) * 16 + quad * 4;
    #pragma unroll
    for (int n2 = 0; n2 < 4; ++n2)
      #pragma unroll
      for (int r = 0; r < 4; ++r)
        out[(size_t)(tokb + r) * 512 + h * 64 + n2 * 16 + l15] = f2bf(o[n2][r]);
    __syncthreads();
  }
}

extern "C" void kernel_launch(void* const* d_in, const int* in_sizes, int n_in,
                              void* d_out, int out_size, void* d_ws, size_t ws_size,
                              hipStream_t stream) {
  const float* x     = (const float*)d_in[0];  // 16384 x 1024 fp32
  const float* w_qkv = (const float*)d_in[1];  // 1024 x 1536 fp32
  const float* w_out = (const float*)d_in[2];  // 512 x 1024 fp32
  const float* b_out = (const float*)d_in[3];  // 1024 fp32
  float* out = (float*)d_out;                  // 16384 x 1024 fp32

  char* ws = (char*)d_ws;
  unsigned short* xb    = (unsigned short*)ws;                     // 16384x1024 bf16 (32 MB)
  unsigned short* wqkvT = (unsigned short*)(ws + 33554432);        // 1536x1024 (3 MB)
  unsigned short* woutT = (unsigned short*)(ws + 36700160);        // 1024x512  (1 MB)
  unsigned short* qkv   = (unsigned short*)(ws + 37748736);        // 16384x1536 (48 MB)
  unsigned short* attno = (unsigned short*)(ws + 88080384);        // 16384x512 (16 MB)

  cast_bf16_k<<<8192, 256, 0, stream>>>(x, xb, 16384 * 1024);
  transpose_cast_k<<<6144, 256, 0, stream>>>(w_qkv, wqkvT, 1024, 1536);
  transpose_cast_k<<<2048, 256, 0, stream>>>(w_out, woutT, 512, 1024);
  gemm_bt<unsigned short><<<dim3(12, 128), 256, 0, stream>>>(
      xb, wqkvT, qkv, nullptr, 16384, 1536, 1024);
  attn_local<<<1024, 256, 0, stream>>>(qkv, attno);
  gemm_bt<float><<<dim3(8, 128), 256, 0, stream>>>(
      attno, woutT, out, b_out, 16384, 1024, 512);
}

// Round 3
// 281.960 us; speedup vs baseline: 1.0201x; 1.0201x over previous
//
#include <hip/hip_runtime.h>

using bf16x8 = __attribute__((ext_vector_type(8))) short;
using f32x4  = __attribute__((ext_vector_type(4))) float;
using u32x4  = __attribute__((ext_vector_type(4))) unsigned int;

__device__ __forceinline__ unsigned short f2bf(float f) {
  unsigned int u = __builtin_bit_cast(unsigned int, f);
  u += 0x7FFF + ((u >> 16) & 1);               // RNE
  return (unsigned short)(u >> 16);
}
__device__ __forceinline__ bf16x8 lds_frag(const unsigned short* p) {
  return __builtin_bit_cast(bf16x8, *(const u32x4*)p);
}
// async global->LDS, 16B per lane; LDS dest = wave-uniform base + lane*16
__device__ __forceinline__ void async_copy16(const unsigned short* g, unsigned short* l) {
  __builtin_amdgcn_global_load_lds(
      (const __attribute__((address_space(1))) unsigned int*)g,
      (__attribute__((address_space(3))) unsigned int*)l, 16, 0, 0);
}

// fp32 -> bf16 elementwise, 8 elems/thread
__global__ void cast_bf16_k(const float* __restrict__ in,
                            unsigned short* __restrict__ out, int n) {
  int i = (blockIdx.x * 256 + threadIdx.x) * 8;
  if (i < n) {
    unsigned short r[8];
    #pragma unroll
    for (int j = 0; j < 8; ++j) r[j] = f2bf(in[i + j]);
    *(u32x4*)&out[i] = *(u32x4*)r;
  }
}

// out[c*R + r] = bf16(in[r*C + c])   (in: R x C fp32, out: C x R bf16)
__global__ void transpose_cast_k(const float* __restrict__ in,
                                 unsigned short* __restrict__ out, int R, int C) {
  int idx = blockIdx.x * 256 + threadIdx.x;
  if (idx < R * C) {
    int c = idx / R, r = idx - c * R;
    out[idx] = f2bf(in[r * C + c]);
  }
}

// C[M,N] = A[M,K] @ Bt[N,K]^T (+bias for fp32 out), A/Bt bf16, fp32 accum.
// 128x128 tile, BK=32, 4 waves in 2x2, 4x4 16x16x32 MFMA tiles per wave.
// Staging via global_load_lds width=16 (m97 pattern).
template <typename OutT>
__global__ __launch_bounds__(256, 2)
void gemm_bt(const unsigned short* __restrict__ A,
             const unsigned short* __restrict__ Bt,
             OutT* __restrict__ C,
             const float* __restrict__ bias,
             int M, int N, int K) {
  __shared__ unsigned short Ash[128 * 32];
  __shared__ unsigned short Bsh[128 * 32];
  const int tid  = threadIdx.x;
  const int wv   = tid >> 6, lane = tid & 63;
  const int quad = lane >> 4, l15 = lane & 15;
  const int wr   = wv >> 1, wc = wv & 1;
  const int m0 = blockIdx.y * 128, n0 = blockIdx.x * 128;

  // staging addresses: linear elem lin in [0,512), row = lin/4, col8 = lin%4*8
  const int lin0 = tid, lin1 = 256 + tid;
  const unsigned short* pA0 = &A[(size_t)(m0 + (lin0 >> 2)) * K + ((lin0 & 3) << 3)];
  const unsigned short* pA1 = &A[(size_t)(m0 + (lin1 >> 2)) * K + ((lin1 & 3) << 3)];
  const unsigned short* pB0 = &Bt[(size_t)(n0 + (lin0 >> 2)) * K + ((lin0 & 3) << 3)];
  const unsigned short* pB1 = &Bt[(size_t)(n0 + (lin1 >> 2)) * K + ((lin1 & 3) << 3)];

  f32x4 acc[4][4];
  #pragma unroll
  for (int i = 0; i < 4; ++i)
    #pragma unroll
    for (int j = 0; j < 4; ++j)
      acc[i][j] = (f32x4){0.f, 0.f, 0.f, 0.f};

  for (int k0 = 0; k0 < K; k0 += 32) {
    async_copy16(pA0 + k0, &Ash[lin0 * 8]);
    async_copy16(pA1 + k0, &Ash[lin1 * 8]);
    async_copy16(pB0 + k0, &Bsh[lin0 * 8]);
    async_copy16(pB1 + k0, &Bsh[lin1 * 8]);
    __syncthreads();
    bf16x8 af[4], bfr[4];
    #pragma unroll
    for (int i = 0; i < 4; ++i)
      af[i] = lds_frag(&Ash[(wr * 64 + i * 16 + l15) * 32 + quad * 8]);
    #pragma unroll
    for (int j = 0; j < 4; ++j)
      bfr[j] = lds_frag(&Bsh[(wc * 64 + j * 16 + l15) * 32 + quad * 8]);
    #pragma unroll
    for (int i = 0; i < 4; ++i)
      #pragma unroll
      for (int j = 0; j < 4; ++j)
        acc[i][j] = __builtin_amdgcn_mfma_f32_16x16x32_bf16(af[i], bfr[j], acc[i][j], 0, 0, 0);
    __syncthreads();
  }

  #pragma unroll
  for (int i = 0; i < 4; ++i) {
    #pragma unroll
    for (int j = 0; j < 4; ++j) {
      int col = n0 + wc * 64 + j * 16 + l15;
      float badd = (bias != nullptr) ? bias[col] : 0.f;
      #pragma unroll
      for (int r = 0; r < 4; ++r) {
        int row = m0 + wr * 64 + i * 16 + quad * 4 + r;
        if constexpr (sizeof(OutT) == 2)
          C[(size_t)row * N + col] = f2bf(acc[i][j][r] + badd);
        else
          C[(size_t)row * N + col] = acc[i][j][r] + badd;
      }
    }
  }
}

// Local attention: one block per (head, window). qkv: 16384 x 1536 bf16,
// out: 16384 x 512 bf16. WSZ=128, lookback window of 128 (zeros for w==0).
// mask: col <= row + 128. scale = 1/8.
__global__ __launch_bounds__(256, 2)
void attn_local(const unsigned short* __restrict__ qkv,
                unsigned short* __restrict__ out) {
  // Ksh layout: [ks(2)][j(256)][32]  (32-col k-tiles -> b128 frag reads, 64B row stride)
  __shared__ unsigned short Ksh[2 * 256 * 32];   // 32 KB
  __shared__ unsigned short Vsh[256 * 64];       // 32 KB, row-major [k][n]
  unsigned short* Psh = Ksh;                     // P overlays K after scores

  const int tid  = threadIdx.x;
  const int wv   = tid >> 6, lane = tid & 63;
  const int quad = lane >> 4, l15 = lane & 15;
  const int h = blockIdx.x & 7, w = blockIdx.x >> 3;

  // stage K (tiled) and V (row-major); rows j<128 of window 0 are zeros
  #pragma unroll
  for (int p = 0; p < 8; ++p) {
    int c = p * 256 + tid;
    int j = c >> 3, sub = c & 7;
    u32x4 kvv = (u32x4){0, 0, 0, 0}, vvv = (u32x4){0, 0, 0, 0};
    if (!(w == 0 && j < 128)) {
      size_t base = (size_t)((w - 1) * 128 + j) * 1536 + h * 64 + sub * 8;
      kvv = *(const u32x4*)&qkv[base + 512];
      vvv = *(const u32x4*)&qkv[base + 1024];
    }
    *(u32x4*)&Ksh[(sub >> 2) * 8192 + j * 32 + (sub & 3) * 8] = kvv;
    *(u32x4*)&Vsh[j * 64 + sub * 8] = vvv;
  }
  __syncthreads();

  // Q fragments straight from global (A-operand layout: row l15, k = ks*32+quad*8..+7)
  bf16x8 qf[2][2];
  #pragma unroll
  for (int mt = 0; mt < 2; ++mt) {
    int tok = w * 128 + (wv * 2 + mt) * 16 + l15;
    #pragma unroll
    for (int ks = 0; ks < 2; ++ks)
      qf[mt][ks] = __builtin_bit_cast(
          bf16x8, *(const u32x4*)&qkv[(size_t)tok * 1536 + h * 64 + ks * 32 + quad * 8]);
  }

  // scores: wave wv owns rows [wv*32, wv*32+32) => m-tiles {2wv, 2wv+1}
  float s[2][16][4];
  #pragma unroll
  for (int nt = 0; nt < 16; ++nt) {
    bf16x8 kf0 = lds_frag(&Ksh[0    + (nt * 16 + l15) * 32 + quad * 8]);
    bf16x8 kf1 = lds_frag(&Ksh[8192 + (nt * 16 + l15) * 32 + quad * 8]);
    #pragma unroll
    for (int mt = 0; mt < 2; ++mt) {
      f32x4 a = (f32x4){0.f, 0.f, 0.f, 0.f};
      a = __builtin_amdgcn_mfma_f32_16x16x32_bf16(qf[mt][0], kf0, a, 0, 0, 0);
      a = __builtin_amdgcn_mfma_f32_16x16x32_bf16(qf[mt][1], kf1, a, 0, 0, 0);
      #pragma unroll
      for (int r = 0; r < 4; ++r) s[mt][nt][r] = a[r];
    }
  }

  // masked softmax in registers (row = mtile*16 + quad*4 + r, col = nt*16 + l15)
  #pragma unroll
  for (int mt = 0; mt < 2; ++mt) {
    int rowb = (wv * 2 + mt) * 16 + quad * 4;
    #pragma unroll
    for (int r = 0; r < 4; ++r) {
      int lim = rowb + r + 128;
      float mx = -3.0e38f;
      #pragma unroll
      for (int nt = 0; nt < 16; ++nt) {
        float v = ((nt * 16 + l15) <= lim) ? s[mt][nt][r] * 0.125f : -3.0e38f;
        s[mt][nt][r] = v;
        mx = fmaxf(mx, v);
      }
      mx = fmaxf(mx, __shfl_xor(mx, 1));
      mx = fmaxf(mx, __shfl_xor(mx, 2));
      mx = fmaxf(mx, __shfl_xor(mx, 4));
      mx = fmaxf(mx, __shfl_xor(mx, 8));
      float sum = 0.f;
      #pragma unroll
      for (int nt = 0; nt < 16; ++nt) {
        float p = __expf(s[mt][nt][r] - mx);   // masked -> exp(-huge) = 0
        s[mt][nt][r] = p;
        sum += p;
      }
      sum += __shfl_xor(sum, 1);
      sum += __shfl_xor(sum, 2);
      sum += __shfl_xor(sum, 4);
      sum += __shfl_xor(sum, 8);
      float inv = 1.f / sum;
      #pragma unroll
      for (int nt = 0; nt < 16; ++nt) s[mt][nt][r] *= inv;
    }
  }

  __syncthreads();   // all waves done reading Ksh -> safe to overlay P

  // PV: per m-tile, round-trip P through per-wave LDS region (C-layout -> A-layout)
  // P region layout per wave: [ks(8)][row(16)][32]  (64B row stride, b128-aligned)
  #pragma unroll
  for (int mt = 0; mt < 2; ++mt) {
    #pragma unroll
    for (int nt = 0; nt < 16; ++nt)
      #pragma unroll
      for (int r = 0; r < 4; ++r)
        Psh[wv * 4096 + (nt >> 1) * 512 + (quad * 4 + r) * 32 + (nt & 1) * 16 + l15] =
            f2bf(s[mt][nt][r]);
    __syncthreads();
    f32x4 o[4];
    #pragma unroll
    for (int n2 = 0; n2 < 4; ++n2) o[n2] = (f32x4){0.f, 0.f, 0.f, 0.f};
    #pragma unroll
    for (int ks = 0; ks < 8; ++ks) {
      bf16x8 pa = lds_frag(&Psh[wv * 4096 + ks * 512 + l15 * 32 + quad * 8]);
      #pragma unroll
      for (int n2 = 0; n2 < 4; ++n2) {
        bf16x8 vb;
        #pragma unroll
        for (int jj = 0; jj < 8; ++jj)
          vb[jj] = (short)Vsh[(ks * 32 + quad * 8 + jj) * 64 + n2 * 16 + l15];
        o[n2] = __builtin_amdgcn_mfma_f32_16x16x32_bf16(pa, vb, o[n2], 0, 0, 0);
      }
    }
    int tokb = w * 128 + (wv * 2 + mt) * 16 + quad * 4;
    #pragma unroll
    for (int n2 = 0; n2 < 4; ++n2)
      #pragma unroll
      for (int r = 0; r < 4; ++r)
        out[(size_t)(tokb + r) * 512 + h * 64 + n2 * 16 + l15] = f2bf(o[n2][r]);
    __syncthreads();
  }
}

extern "C" void kernel_launch(void* const* d_in, const int* in_sizes, int n_in,
                              void* d_out, int out_size, void* d_ws, size_t ws_size,
                              hipStream_t stream) {
  const float* x     = (const float*)d_in[0];  // 16384 x 1024 fp32
  const float* w_qkv = (const float*)d_in[1];  // 1024 x 1536 fp32
  const float* w_out = (const float*)d_in[2];  // 512 x 1024 fp32
  const float* b_out = (const float*)d_in[3];  // 1024 fp32
  float* out = (float*)d_out;                  // 16384 x 1024 fp32

  char* ws = (char*)d_ws;
  unsigned short* xb    = (unsigned short*)ws;                     // 16384x1024 bf16 (32 MB)
  unsigned short* wqkvT = (unsigned short*)(ws + 33554432);        // 1536x1024 (3 MB)
  unsigned short* woutT = (unsigned short*)(ws + 36700160);        // 1024x512  (1 MB)
  unsigned short* qkv   = (unsigned short*)(ws + 37748736);        // 16384x1536 (48 MB)
  unsigned short* attno = (unsigned short*)(ws + 88080384);        // 16384x512 (16 MB)

  cast_bf16_k<<<8192, 256, 0, stream>>>(x, xb, 16384 * 1024);
  transpose_cast_k<<<6144, 256, 0, stream>>>(w_qkv, wqkvT, 1024, 1536);
  transpose_cast_k<<<2048, 256, 0, stream>>>(w_out, woutT, 512, 1024);
  gemm_bt<unsigned short><<<dim3(12, 128), 256, 0, stream>>>(
      xb, wqkvT, qkv, nullptr, 16384, 1536, 1024);
  attn_local<<<1024, 256, 0, stream>>>(qkv, attno);
  gemm_bt<float><<<dim3(8, 128), 256, 0, stream>>>(
      attno, woutT, out, b_out, 16384, 1024, 512);
}

// Round 4
// 264.458 us; speedup vs baseline: 1.0876x; 1.0662x over previous
//
#include <hip/hip_runtime.h>

using bf16x8 = __attribute__((ext_vector_type(8))) short;
using f32x4  = __attribute__((ext_vector_type(4))) float;
using u32x4  = __attribute__((ext_vector_type(4))) unsigned int;

__device__ __forceinline__ unsigned short f2bf(float f) {
  unsigned int u = __builtin_bit_cast(unsigned int, f);
  u += 0x7FFF + ((u >> 16) & 1);               // RNE
  return (unsigned short)(u >> 16);
}
__device__ __forceinline__ bf16x8 lds_frag(const unsigned short* p) {
  return __builtin_bit_cast(bf16x8, *(const u32x4*)p);
}
// async global->LDS, 16B per lane; LDS dest = wave-uniform base + lane*16
__device__ __forceinline__ void async_copy16(const unsigned short* g, unsigned short* l) {
  __builtin_amdgcn_global_load_lds(
      (const __attribute__((address_space(1))) unsigned int*)g,
      (__attribute__((address_space(3))) unsigned int*)l, 16, 0, 0);
}

// fp32 -> bf16 elementwise, 8 elems/thread
__global__ void cast_bf16_k(const float* __restrict__ in,
                            unsigned short* __restrict__ out, int n) {
  int i = (blockIdx.x * 256 + threadIdx.x) * 8;
  if (i < n) {
    unsigned short r[8];
    #pragma unroll
    for (int j = 0; j < 8; ++j) r[j] = f2bf(in[i + j]);
    *(u32x4*)&out[i] = *(u32x4*)r;
  }
}

// out[c*R + r] = bf16(in[r*C + c])   (in: R x C fp32, out: C x R bf16)
__global__ void transpose_cast_k(const float* __restrict__ in,
                                 unsigned short* __restrict__ out, int R, int C) {
  int idx = blockIdx.x * 256 + threadIdx.x;
  if (idx < R * C) {
    int c = idx / R, r = idx - c * R;
    out[idx] = f2bf(in[r * C + c]);
  }
}

// C[M,N] = A[M,K] @ Bt[N,K]^T (+bias for fp32 out), A/Bt bf16, fp32 accum.
// 128x128 tile, BK=32, global_load_lds staging.
// XCD-aware swizzle: xcd = blockIdx%8 owns M-panel [xcd*mt_per_xcd, ...),
// N-tiles iterate fastest -> A-tile fetched by ONE xcd; B resident in its L2.
template <typename OutT>
__global__ __launch_bounds__(256, 2)
void gemm_bt(const unsigned short* __restrict__ A,
             const unsigned short* __restrict__ Bt,
             OutT* __restrict__ C,
             const float* __restrict__ bias,
             int M, int N, int K, int n_tiles, int mt_per_xcd) {
  __shared__ unsigned short Ash[128 * 32];
  __shared__ unsigned short Bsh[128 * 32];
  const int tid  = threadIdx.x;
  const int wv   = tid >> 6, lane = tid & 63;
  const int quad = lane >> 4, l15 = lane & 15;
  const int wr   = wv >> 1, wc = wv & 1;

  const int b = blockIdx.x;
  const int xcd = b & 7, local = b >> 3;
  const int mt = xcd * mt_per_xcd + local / n_tiles;
  const int nt = local % n_tiles;
  const int m0 = mt * 128, n0 = nt * 128;

  // staging addresses: linear elem lin in [0,512), row = lin/4, col8 = lin%4*8
  const int lin0 = tid, lin1 = 256 + tid;
  const unsigned short* pA0 = &A[(size_t)(m0 + (lin0 >> 2)) * K + ((lin0 & 3) << 3)];
  const unsigned short* pA1 = &A[(size_t)(m0 + (lin1 >> 2)) * K + ((lin1 & 3) << 3)];
  const unsigned short* pB0 = &Bt[(size_t)(n0 + (lin0 >> 2)) * K + ((lin0 & 3) << 3)];
  const unsigned short* pB1 = &Bt[(size_t)(n0 + (lin1 >> 2)) * K + ((lin1 & 3) << 3)];

  f32x4 acc[4][4];
  #pragma unroll
  for (int i = 0; i < 4; ++i)
    #pragma unroll
    for (int j = 0; j < 4; ++j)
      acc[i][j] = (f32x4){0.f, 0.f, 0.f, 0.f};

  for (int k0 = 0; k0 < K; k0 += 32) {
    async_copy16(pA0 + k0, &Ash[lin0 * 8]);
    async_copy16(pA1 + k0, &Ash[lin1 * 8]);
    async_copy16(pB0 + k0, &Bsh[lin0 * 8]);
    async_copy16(pB1 + k0, &Bsh[lin1 * 8]);
    __syncthreads();
    bf16x8 af[4], bfr[4];
    #pragma unroll
    for (int i = 0; i < 4; ++i)
      af[i] = lds_frag(&Ash[(wr * 64 + i * 16 + l15) * 32 + quad * 8]);
    #pragma unroll
    for (int j = 0; j < 4; ++j)
      bfr[j] = lds_frag(&Bsh[(wc * 64 + j * 16 + l15) * 32 + quad * 8]);
    #pragma unroll
    for (int i = 0; i < 4; ++i)
      #pragma unroll
      for (int j = 0; j < 4; ++j)
        acc[i][j] = __builtin_amdgcn_mfma_f32_16x16x32_bf16(af[i], bfr[j], acc[i][j], 0, 0, 0);
    __syncthreads();
  }

  #pragma unroll
  for (int i = 0; i < 4; ++i) {
    #pragma unroll
    for (int j = 0; j < 4; ++j) {
      int col = n0 + wc * 64 + j * 16 + l15;
      float badd = (bias != nullptr) ? bias[col] : 0.f;
      #pragma unroll
      for (int r = 0; r < 4; ++r) {
        int row = m0 + wr * 64 + i * 16 + quad * 4 + r;
        if constexpr (sizeof(OutT) == 2)
          C[(size_t)row * N + col] = f2bf(acc[i][j][r] + badd);
        else
          C[(size_t)row * N + col] = acc[i][j][r] + badd;
      }
    }
  }
}

// Local attention: one block per (head, window). qkv: 16384 x 1536 bf16,
// out: 16384 x 512 bf16. WSZ=128, lookback window of 128 (zeros for w==0).
// mask: col <= row + 128. scale = 1/8.
__global__ __launch_bounds__(256, 2)
void attn_local(const unsigned short* __restrict__ qkv,
                unsigned short* __restrict__ out) {
  // Ksh: [ks(2)][j(256)][32] (64B rows -> b128 frags). Psh overlays Ksh.
  // VshT: V transposed, [n(64)][k stride 272] -> PV B-frags are ds_read_b128.
  //   row stride 272 elems = 544 B (16B-aligned, ~4-way bank conflict = 1.58x)
  __shared__ unsigned short Ksh[2 * 256 * 32];   // 32 KB
  __shared__ unsigned short VshT[64 * 272];      // 34 KB
  unsigned short* Psh = Ksh;

  const int tid  = threadIdx.x;
  const int wv   = tid >> 6, lane = tid & 63;
  const int quad = lane >> 4, l15 = lane & 15;
  const int h = blockIdx.x & 7, w = blockIdx.x >> 3;

  // stage K (k-tiled); rows j<128 of window 0 are zeros
  #pragma unroll
  for (int p = 0; p < 4; ++p) {
    int c = p * 256 + tid;                 // 1024 vec8 slots = 256 rows x 4
    int j = c >> 2, sub = c & 3;           // sub: 8-elem group within 32... wait
    // K row j has 64 elems = 8 vec8 groups; re-derive: c over 2048 groups
    (void)j; (void)sub;
  }
  // (loop above unused; real K staging below)
  #pragma unroll
  for (int p = 0; p < 8; ++p) {
    int c = p * 256 + tid;                 // 2048 = 256 rows x 8 vec8-groups
    int j = c >> 3, sub = c & 7;
    u32x4 kvv = (u32x4){0, 0, 0, 0};
    if (!(w == 0 && j < 128)) {
      size_t base = (size_t)((w - 1) * 128 + j) * 1536 + h * 64 + sub * 8;
      kvv = *(const u32x4*)&qkv[base + 512];
    }
    *(u32x4*)&Ksh[(sub >> 2) * 8192 + j * 32 + (sub & 3) * 8] = kvv;
  }
  // stage V^T: thread (n = tid&63, kb4 = tid>>6) loads column n, 8 k's per iter
  {
    const int n = tid & 63, kb4 = tid >> 6;
    #pragma unroll
    for (int kk = 0; kk < 8; ++kk) {
      int kb = kk * 4 + kb4;               // 0..31, k0 = kb*8
      unsigned short tmp[8];
      if (w == 0 && kb < 16) {
        #pragma unroll
        for (int j = 0; j < 8; ++j) tmp[j] = 0;
      } else {
        #pragma unroll
        for (int j = 0; j < 8; ++j)
          tmp[j] = qkv[(size_t)((w - 1) * 128 + kb * 8 + j) * 1536 + 1024 + h * 64 + n];
      }
      *(u32x4*)&VshT[n * 272 + kb * 8] = *(u32x4*)tmp;
    }
  }
  __syncthreads();

  // Q fragments straight from global (A-operand: row l15, k = ks*32+quad*8..+7)
  bf16x8 qf[2][2];
  #pragma unroll
  for (int mt = 0; mt < 2; ++mt) {
    int tok = w * 128 + (wv * 2 + mt) * 16 + l15;
    #pragma unroll
    for (int ks = 0; ks < 2; ++ks)
      qf[mt][ks] = __builtin_bit_cast(
          bf16x8, *(const u32x4*)&qkv[(size_t)tok * 1536 + h * 64 + ks * 32 + quad * 8]);
  }

  // scores: wave wv owns rows [wv*32, wv*32+32) => m-tiles {2wv, 2wv+1}
  float s[2][16][4];
  #pragma unroll
  for (int nt = 0; nt < 16; ++nt) {
    bf16x8 kf0 = lds_frag(&Ksh[0    + (nt * 16 + l15) * 32 + quad * 8]);
    bf16x8 kf1 = lds_frag(&Ksh[8192 + (nt * 16 + l15) * 32 + quad * 8]);
    #pragma unroll
    for (int mt = 0; mt < 2; ++mt) {
      f32x4 a = (f32x4){0.f, 0.f, 0.f, 0.f};
      a = __builtin_amdgcn_mfma_f32_16x16x32_bf16(qf[mt][0], kf0, a, 0, 0, 0);
      a = __builtin_amdgcn_mfma_f32_16x16x32_bf16(qf[mt][1], kf1, a, 0, 0, 0);
      #pragma unroll
      for (int r = 0; r < 4; ++r) s[mt][nt][r] = a[r];
    }
  }

  // masked softmax in registers (row = mtile*16 + quad*4 + r, col = nt*16 + l15)
  #pragma unroll
  for (int mt = 0; mt < 2; ++mt) {
    int rowb = (wv * 2 + mt) * 16 + quad * 4;
    #pragma unroll
    for (int r = 0; r < 4; ++r) {
      int lim = rowb + r + 128;
      float mx = -3.0e38f;
      #pragma unroll
      for (int nt = 0; nt < 16; ++nt) {
        float v = ((nt * 16 + l15) <= lim) ? s[mt][nt][r] * 0.125f : -3.0e38f;
        s[mt][nt][r] = v;
        mx = fmaxf(mx, v);
      }
      mx = fmaxf(mx, __shfl_xor(mx, 1));
      mx = fmaxf(mx, __shfl_xor(mx, 2));
      mx = fmaxf(mx, __shfl_xor(mx, 4));
      mx = fmaxf(mx, __shfl_xor(mx, 8));
      float sum = 0.f;
      #pragma unroll
      for (int nt = 0; nt < 16; ++nt) {
        float p = __expf(s[mt][nt][r] - mx);   // masked -> exp(-huge) = 0
        s[mt][nt][r] = p;
        sum += p;
      }
      sum += __shfl_xor(sum, 1);
      sum += __shfl_xor(sum, 2);
      sum += __shfl_xor(sum, 4);
      sum += __shfl_xor(sum, 8);
      float inv = 1.f / sum;
      #pragma unroll
      for (int nt = 0; nt < 16; ++nt) s[mt][nt][r] *= inv;
    }
  }

  __syncthreads();   // all waves done reading Ksh -> safe to overlay P

  // PV: per m-tile, round-trip P through per-wave LDS region (C-layout -> A-layout)
  // P region layout per wave: [ks(8)][row(16)][32]
  #pragma unroll
  for (int mt = 0; mt < 2; ++mt) {
    #pragma unroll
    for (int nt = 0; nt < 16; ++nt)
      #pragma unroll
      for (int r = 0; r < 4; ++r)
        Psh[wv * 4096 + (nt >> 1) * 512 + (quad * 4 + r) * 32 + (nt & 1) * 16 + l15] =
            f2bf(s[mt][nt][r]);
    __syncthreads();
    f32x4 o[4];
    #pragma unroll
    for (int n2 = 0; n2 < 4; ++n2) o[n2] = (f32x4){0.f, 0.f, 0.f, 0.f};
    #pragma unroll
    for (int ks = 0; ks < 8; ++ks) {
      bf16x8 pa = lds_frag(&Psh[wv * 4096 + ks * 512 + l15 * 32 + quad * 8]);
      #pragma unroll
      for (int n2 = 0; n2 < 4; ++n2) {
        // B-frag: col n = n2*16+l15, k = ks*32+quad*8..+7 -> VshT[n][k], b128
        bf16x8 vb = lds_frag(&VshT[(n2 * 16 + l15) * 272 + ks * 32 + quad * 8]);
        o[n2] = __builtin_amdgcn_mfma_f32_16x16x32_bf16(pa, vb, o[n2], 0, 0, 0);
      }
    }
    int tokb = w * 128 + (wv * 2 + mt) * 16 + quad * 4;
    #pragma unroll
    for (int n2 = 0; n2 < 4; ++n2)
      #pragma unroll
      for (int r = 0; r < 4; ++r)
        out[(size_t)(tokb + r) * 512 + h * 64 + n2 * 16 + l15] = f2bf(o[n2][r]);
    __syncthreads();
  }
}

extern "C" void kernel_launch(void* const* d_in, const int* in_sizes, int n_in,
                              void* d_out, int out_size, void* d_ws, size_t ws_size,
                              hipStream_t stream) {
  const float* x     = (const float*)d_in[0];  // 16384 x 1024 fp32
  const float* w_qkv = (const float*)d_in[1];  // 1024 x 1536 fp32
  const float* w_out = (const float*)d_in[2];  // 512 x 1024 fp32
  const float* b_out = (const float*)d_in[3];  // 1024 fp32
  float* out = (float*)d_out;                  // 16384 x 1024 fp32

  char* ws = (char*)d_ws;
  unsigned short* xb    = (unsigned short*)ws;                     // 16384x1024 bf16 (32 MB)
  unsigned short* wqkvT = (unsigned short*)(ws + 33554432);        // 1536x1024 (3 MB)
  unsigned short* woutT = (unsigned short*)(ws + 36700160);        // 1024x512  (1 MB)
  unsigned short* qkv   = (unsigned short*)(ws + 37748736);        // 16384x1536 (48 MB)
  unsigned short* attno = (unsigned short*)(ws + 88080384);        // 16384x512 (16 MB)

  cast_bf16_k<<<8192, 256, 0, stream>>>(x, xb, 16384 * 1024);
  transpose_cast_k<<<6144, 256, 0, stream>>>(w_qkv, wqkvT, 1024, 1536);
  transpose_cast_k<<<2048, 256, 0, stream>>>(w_out, woutT, 512, 1024);
  // QKV: 128 m-tiles x 12 n-tiles; 16 m-tiles per xcd
  gemm_bt<unsigned short><<<1536, 256, 0, stream>>>(
      xb, wqkvT, qkv, nullptr, 16384, 1536, 1024, 12, 16);
  attn_local<<<1024, 256, 0, stream>>>(qkv, attno);
  // out-proj: 128 m-tiles x 8 n-tiles; 16 m-tiles per xcd
  gemm_bt<float><<<1024, 256, 0, stream>>>(
      attno, woutT, out, b_out, 16384, 1024, 512, 8, 16);
}

// Round 5
// 239.829 us; speedup vs baseline: 1.1993x; 1.1027x over previous
//
#include <hip/hip_runtime.h>

using bf16x8 = __attribute__((ext_vector_type(8))) short;
using f32x4  = __attribute__((ext_vector_type(4))) float;
using u32x4  = __attribute__((ext_vector_type(4))) unsigned int;

__device__ __forceinline__ unsigned short f2bf(float f) {
  unsigned int u = __builtin_bit_cast(unsigned int, f);
  u += 0x7FFF + ((u >> 16) & 1);               // RNE
  return (unsigned short)(u >> 16);
}
__device__ __forceinline__ bf16x8 lds_frag(const unsigned short* p) {
  return __builtin_bit_cast(bf16x8, *(const u32x4*)p);
}
// async global->LDS, 16B per lane; LDS dest = wave-uniform base + lane*16
__device__ __forceinline__ void async_copy16(const unsigned short* g, unsigned short* l) {
  __builtin_amdgcn_global_load_lds(
      (const __attribute__((address_space(1))) unsigned int*)g,
      (__attribute__((address_space(3))) unsigned int*)l, 16, 0, 0);
}

// fp32 -> bf16 elementwise, 8 elems/thread
__global__ void cast_bf16_k(const float* __restrict__ in,
                            unsigned short* __restrict__ out, int n) {
  int i = (blockIdx.x * 256 + threadIdx.x) * 8;
  if (i < n) {
    unsigned short r[8];
    #pragma unroll
    for (int j = 0; j < 8; ++j) r[j] = f2bf(in[i + j]);
    *(u32x4*)&out[i] = *(u32x4*)r;
  }
}

// LDS-tiled transpose+cast: out[c*R+r] = bf16(in[r*C+c]). R,C multiples of 32.
__global__ void transpose_cast_k(const float* __restrict__ in,
                                 unsigned short* __restrict__ out, int R, int C) {
  __shared__ float tile[32][33];
  const int tx = threadIdx.x & 31, ty = threadIdx.x >> 5;   // 32 x 8
  const int c0 = blockIdx.x * 32, r0 = blockIdx.y * 32;
  #pragma unroll
  for (int i = 0; i < 4; ++i)
    tile[ty + i * 8][tx] = in[(size_t)(r0 + ty + i * 8) * C + c0 + tx];
  __syncthreads();
  #pragma unroll
  for (int i = 0; i < 4; ++i)
    out[(size_t)(c0 + ty + i * 8) * R + r0 + tx] = f2bf(tile[tx][ty + i * 8]);
}

// C[M,N] = A[M,K] @ Bt[N,K]^T (+bias for fp32 out), A/Bt bf16, fp32 accum.
// 128x128 tile, BK=64, global_load_lds staging with XOR bank swizzle:
//   16B-group cg of row r lives at LDS slot (cg ^ (r&7)); permutation applied
//   on the per-lane GLOBAL address (coalescing kept within 128B segments),
//   LDS dest stays base + lane*16. Frag reads then hit 2-way banks (free).
// XCD swizzle: xcd = blockIdx%8 owns an M-panel; N-tiles iterate fastest.
template <typename OutT>
__global__ __launch_bounds__(256, 2)
void gemm_bt(const unsigned short* __restrict__ A,
             const unsigned short* __restrict__ Bt,
             OutT* __restrict__ C,
             const float* __restrict__ bias,
             int M, int N, int K, int n_tiles, int mt_per_xcd) {
  __shared__ unsigned short Ash[128 * 64];   // 16 KB
  __shared__ unsigned short Bsh[128 * 64];   // 16 KB
  const int tid  = threadIdx.x;
  const int wv   = tid >> 6, lane = tid & 63;
  const int quad = lane >> 4, l15 = lane & 15;
  const int wr   = wv >> 1, wc = wv & 1;

  const int b = blockIdx.x;
  const int xcd = b & 7, local = b >> 3;
  const int mt = xcd * mt_per_xcd + local / n_tiles;
  const int nt = local % n_tiles;
  const int m0 = mt * 128, n0 = nt * 128;

  // staging: 1024 16B-groups per matrix; p in 0..3, lin = p*256+tid
  // LDS slot lin = (row = lin>>3, cg = lin&7); global group = cg ^ (row&7)
  const unsigned short* pA[4];
  const unsigned short* pB[4];
  #pragma unroll
  for (int p = 0; p < 4; ++p) {
    int lin = p * 256 + tid;
    int row = lin >> 3, g = (lin & 7) ^ (row & 7);
    pA[p] = &A[(size_t)(m0 + row) * K + g * 8];
    pB[p] = &Bt[(size_t)(n0 + row) * K + g * 8];
  }

  f32x4 acc[4][4];
  #pragma unroll
  for (int i = 0; i < 4; ++i)
    #pragma unroll
    for (int j = 0; j < 4; ++j)
      acc[i][j] = (f32x4){0.f, 0.f, 0.f, 0.f};

  for (int k0 = 0; k0 < K; k0 += 64) {
    #pragma unroll
    for (int p = 0; p < 4; ++p)
      async_copy16(pA[p] + k0, &Ash[(p * 256 + tid) * 8]);
    #pragma unroll
    for (int p = 0; p < 4; ++p)
      async_copy16(pB[p] + k0, &Bsh[(p * 256 + tid) * 8]);
    __syncthreads();
    #pragma unroll
    for (int ks = 0; ks < 2; ++ks) {
      // element (row=l15-ish, k=ks*32+quad*8..+7): group ks*4+quad, swizzled
      const int swz = (((ks * 4 + quad) ^ (l15 & 7)) * 8);
      bf16x8 af[4], bfr[4];
      #pragma unroll
      for (int i = 0; i < 4; ++i)
        af[i] = lds_frag(&Ash[(wr * 64 + i * 16 + l15) * 64 + swz]);
      #pragma unroll
      for (int j = 0; j < 4; ++j)
        bfr[j] = lds_frag(&Bsh[(wc * 64 + j * 16 + l15) * 64 + swz]);
      #pragma unroll
      for (int i = 0; i < 4; ++i)
        #pragma unroll
        for (int j = 0; j < 4; ++j)
          acc[i][j] = __builtin_amdgcn_mfma_f32_16x16x32_bf16(af[i], bfr[j], acc[i][j], 0, 0, 0);
    }
    __syncthreads();
  }

  #pragma unroll
  for (int i = 0; i < 4; ++i) {
    #pragma unroll
    for (int j = 0; j < 4; ++j) {
      int col = n0 + wc * 64 + j * 16 + l15;
      float badd = (bias != nullptr) ? bias[col] : 0.f;
      #pragma unroll
      for (int r = 0; r < 4; ++r) {
        int row = m0 + wr * 64 + i * 16 + quad * 4 + r;
        if constexpr (sizeof(OutT) == 2)
          C[(size_t)row * N + col] = f2bf(acc[i][j][r] + badd);
        else
          C[(size_t)row * N + col] = acc[i][j][r] + badd;
      }
    }
  }
}

// Local attention: one block per (head, window). qkv: 16384 x 1536 bf16,
// out: 16384 x 512 bf16. WSZ=128, lookback window of 128 (zeros for w==0).
// mask: col <= row + 128. scale = 1/8.
__global__ __launch_bounds__(256, 2)
void attn_local(const unsigned short* __restrict__ qkv,
                unsigned short* __restrict__ out) {
  // Ksh: [ks(2)][j(256)][32] (64B rows -> b128 frags). Psh overlays Ksh.
  // VshT: V transposed, [n(64)][k stride 272] -> PV B-frags are ds_read_b128.
  __shared__ unsigned short Ksh[2 * 256 * 32];   // 32 KB
  __shared__ unsigned short VshT[64 * 272];      // 34 KB
  unsigned short* Psh = Ksh;

  const int tid  = threadIdx.x;
  const int wv   = tid >> 6, lane = tid & 63;
  const int quad = lane >> 4, l15 = lane & 15;
  const int h = blockIdx.x & 7, w = blockIdx.x >> 3;

  // stage K (k-tiled); rows j<128 of window 0 are zeros
  #pragma unroll
  for (int p = 0; p < 8; ++p) {
    int c = p * 256 + tid;                 // 2048 = 256 rows x 8 vec8-groups
    int j = c >> 3, sub = c & 7;
    u32x4 kvv = (u32x4){0, 0, 0, 0};
    if (!(w == 0 && j < 128)) {
      size_t base = (size_t)((w - 1) * 128 + j) * 1536 + h * 64 + sub * 8;
      kvv = *(const u32x4*)&qkv[base + 512];
    }
    *(u32x4*)&Ksh[(sub >> 2) * 8192 + j * 32 + (sub & 3) * 8] = kvv;
  }
  // stage V^T: thread (n = tid&63, kb4 = tid>>6) loads column n, 8 k's per iter
  {
    const int n = tid & 63, kb4 = tid >> 6;
    #pragma unroll
    for (int kk = 0; kk < 8; ++kk) {
      int kb = kk * 4 + kb4;               // 0..31, k0 = kb*8
      unsigned short tmp[8];
      if (w == 0 && kb < 16) {
        #pragma unroll
        for (int j = 0; j < 8; ++j) tmp[j] = 0;
      } else {
        #pragma unroll
        for (int j = 0; j < 8; ++j)
          tmp[j] = qkv[(size_t)((w - 1) * 128 + kb * 8 + j) * 1536 + 1024 + h * 64 + n];
      }
      *(u32x4*)&VshT[n * 272 + kb * 8] = *(u32x4*)tmp;
    }
  }
  __syncthreads();

  // Q fragments straight from global (A-operand: row l15, k = ks*32+quad*8..+7)
  bf16x8 qf[2][2];
  #pragma unroll
  for (int mt = 0; mt < 2; ++mt) {
    int tok = w * 128 + (wv * 2 + mt) * 16 + l15;
    #pragma unroll
    for (int ks = 0; ks < 2; ++ks)
      qf[mt][ks] = __builtin_bit_cast(
          bf16x8, *(const u32x4*)&qkv[(size_t)tok * 1536 + h * 64 + ks * 32 + quad * 8]);
  }

  // scores: wave wv owns rows [wv*32, wv*32+32) => m-tiles {2wv, 2wv+1}
  float s[2][16][4];
  #pragma unroll
  for (int nt = 0; nt < 16; ++nt) {
    bf16x8 kf0 = lds_frag(&Ksh[0    + (nt * 16 + l15) * 32 + quad * 8]);
    bf16x8 kf1 = lds_frag(&Ksh[8192 + (nt * 16 + l15) * 32 + quad * 8]);
    #pragma unroll
    for (int mt = 0; mt < 2; ++mt) {
      f32x4 a = (f32x4){0.f, 0.f, 0.f, 0.f};
      a = __builtin_amdgcn_mfma_f32_16x16x32_bf16(qf[mt][0], kf0, a, 0, 0, 0);
      a = __builtin_amdgcn_mfma_f32_16x16x32_bf16(qf[mt][1], kf1, a, 0, 0, 0);
      #pragma unroll
      for (int r = 0; r < 4; ++r) s[mt][nt][r] = a[r];
    }
  }

  // masked softmax in registers (row = mtile*16 + quad*4 + r, col = nt*16 + l15)
  #pragma unroll
  for (int mt = 0; mt < 2; ++mt) {
    int rowb = (wv * 2 + mt) * 16 + quad * 4;
    #pragma unroll
    for (int r = 0; r < 4; ++r) {
      int lim = rowb + r + 128;
      float mx = -3.0e38f;
      #pragma unroll
      for (int nt = 0; nt < 16; ++nt) {
        float v = ((nt * 16 + l15) <= lim) ? s[mt][nt][r] * 0.125f : -3.0e38f;
        s[mt][nt][r] = v;
        mx = fmaxf(mx, v);
      }
      mx = fmaxf(mx, __shfl_xor(mx, 1));
      mx = fmaxf(mx, __shfl_xor(mx, 2));
      mx = fmaxf(mx, __shfl_xor(mx, 4));
      mx = fmaxf(mx, __shfl_xor(mx, 8));
      float sum = 0.f;
      #pragma unroll
      for (int nt = 0; nt < 16; ++nt) {
        float p = __expf(s[mt][nt][r] - mx);   // masked -> exp(-huge) = 0
        s[mt][nt][r] = p;
        sum += p;
      }
      sum += __shfl_xor(sum, 1);
      sum += __shfl_xor(sum, 2);
      sum += __shfl_xor(sum, 4);
      sum += __shfl_xor(sum, 8);
      float inv = 1.f / sum;
      #pragma unroll
      for (int nt = 0; nt < 16; ++nt) s[mt][nt][r] *= inv;
    }
  }

  __syncthreads();   // all waves done reading Ksh -> safe to overlay P

  // PV: per m-tile, round-trip P through per-wave LDS region (C-layout -> A-layout)
  #pragma unroll
  for (int mt = 0; mt < 2; ++mt) {
    #pragma unroll
    for (int nt = 0; nt < 16; ++nt)
      #pragma unroll
      for (int r = 0; r < 4; ++r)
        Psh[wv * 4096 + (nt >> 1) * 512 + (quad * 4 + r) * 32 + (nt & 1) * 16 + l15] =
            f2bf(s[mt][nt][r]);
    __syncthreads();
    f32x4 o[4];
    #pragma unroll
    for (int n2 = 0; n2 < 4; ++n2) o[n2] = (f32x4){0.f, 0.f, 0.f, 0.f};
    #pragma unroll
    for (int ks = 0; ks < 8; ++ks) {
      bf16x8 pa = lds_frag(&Psh[wv * 4096 + ks * 512 + l15 * 32 + quad * 8]);
      #pragma unroll
      for (int n2 = 0; n2 < 4; ++n2) {
        bf16x8 vb = lds_frag(&VshT[(n2 * 16 + l15) * 272 + ks * 32 + quad * 8]);
        o[n2] = __builtin_amdgcn_mfma_f32_16x16x32_bf16(pa, vb, o[n2], 0, 0, 0);
      }
    }
    int tokb = w * 128 + (wv * 2 + mt) * 16 + quad * 4;
    #pragma unroll
    for (int n2 = 0; n2 < 4; ++n2)
      #pragma unroll
      for (int r = 0; r < 4; ++r)
        out[(size_t)(tokb + r) * 512 + h * 64 + n2 * 16 + l15] = f2bf(o[n2][r]);
    __syncthreads();
  }
}

extern "C" void kernel_launch(void* const* d_in, const int* in_sizes, int n_in,
                              void* d_out, int out_size, void* d_ws, size_t ws_size,
                              hipStream_t stream) {
  const float* x     = (const float*)d_in[0];  // 16384 x 1024 fp32
  const float* w_qkv = (const float*)d_in[1];  // 1024 x 1536 fp32
  const float* w_out = (const float*)d_in[2];  // 512 x 1024 fp32
  const float* b_out = (const float*)d_in[3];  // 1024 fp32
  float* out = (float*)d_out;                  // 16384 x 1024 fp32

  char* ws = (char*)d_ws;
  unsigned short* xb    = (unsigned short*)ws;                     // 16384x1024 bf16 (32 MB)
  unsigned short* wqkvT = (unsigned short*)(ws + 33554432);        // 1536x1024 (3 MB)
  unsigned short* woutT = (unsigned short*)(ws + 36700160);        // 1024x512  (1 MB)
  unsigned short* qkv   = (unsigned short*)(ws + 37748736);        // 16384x1536 (48 MB)
  unsigned short* attno = (unsigned short*)(ws + 88080384);        // 16384x512 (16 MB)

  cast_bf16_k<<<8192, 256, 0, stream>>>(x, xb, 16384 * 1024);
  transpose_cast_k<<<dim3(48, 32), 256, 0, stream>>>(w_qkv, wqkvT, 1024, 1536);
  transpose_cast_k<<<dim3(32, 16), 256, 0, stream>>>(w_out, woutT, 512, 1024);
  // QKV: 128 m-tiles x 12 n-tiles; 16 m-tiles per xcd
  gemm_bt<unsigned short><<<1536, 256, 0, stream>>>(
      xb, wqkvT, qkv, nullptr, 16384, 1536, 1024, 12, 16);
  attn_local<<<1024, 256, 0, stream>>>(qkv, attno);
  // out-proj: 128 m-tiles x 8 n-tiles; 16 m-tiles per xcd
  gemm_bt<float><<<1024, 256, 0, stream>>>(
      attno, woutT, out, b_out, 16384, 1024, 512, 8, 16);
}

// Round 6
// 238.593 us; speedup vs baseline: 1.2055x; 1.0052x over previous
//
#include <hip/hip_runtime.h>

using bf16x8 = __attribute__((ext_vector_type(8))) short;
using f32x4  = __attribute__((ext_vector_type(4))) float;
using u32x4  = __attribute__((ext_vector_type(4))) unsigned int;

__device__ __forceinline__ unsigned short f2bf(float f) {
  unsigned int u = __builtin_bit_cast(unsigned int, f);
  u += 0x7FFF + ((u >> 16) & 1);               // RNE
  return (unsigned short)(u >> 16);
}
__device__ __forceinline__ bf16x8 lds_frag(const unsigned short* p) {
  return __builtin_bit_cast(bf16x8, *(const u32x4*)p);
}
// async global->LDS, 16B per lane; LDS dest = wave-uniform base + lane*16
__device__ __forceinline__ void async_copy16(const unsigned short* g, unsigned short* l) {
  __builtin_amdgcn_global_load_lds(
      (const __attribute__((address_space(1))) unsigned int*)g,
      (__attribute__((address_space(3))) unsigned int*)l, 16, 0, 0);
}

// fp32 -> bf16 elementwise, 8 elems/thread
__global__ void cast_bf16_k(const float* __restrict__ in,
                            unsigned short* __restrict__ out, int n) {
  int i = (blockIdx.x * 256 + threadIdx.x) * 8;
  if (i < n) {
    unsigned short r[8];
    #pragma unroll
    for (int j = 0; j < 8; ++j) r[j] = f2bf(in[i + j]);
    *(u32x4*)&out[i] = *(u32x4*)r;
  }
}

// LDS-tiled transpose+cast: out[c*R+r] = bf16(in[r*C+c]). R,C multiples of 32.
__global__ void transpose_cast_k(const float* __restrict__ in,
                                 unsigned short* __restrict__ out, int R, int C) {
  __shared__ float tile[32][33];
  const int tx = threadIdx.x & 31, ty = threadIdx.x >> 5;   // 32 x 8
  const int c0 = blockIdx.x * 32, r0 = blockIdx.y * 32;
  #pragma unroll
  for (int i = 0; i < 4; ++i)
    tile[ty + i * 8][tx] = in[(size_t)(r0 + ty + i * 8) * C + c0 + tx];
  __syncthreads();
  #pragma unroll
  for (int i = 0; i < 4; ++i)
    out[(size_t)(c0 + ty + i * 8) * R + r0 + tx] = f2bf(tile[tx][ty + i * 8]);
}

// C[M,N] = A[M,K] @ Bt[N,K]^T (+bias for fp32 out), A/Bt bf16, fp32 accum.
// 128x128 tile, BK=64, global_load_lds staging with XOR bank swizzle
// (conflict-free, verified r5: SQ_LDS_BANK_CONFLICT == 0).
// launch_bounds (256,3): 3 blocks/CU (r5 had 2.36 at (256,2)) — occupancy probe
// against the 912 TF m97-structure plateau.
template <typename OutT>
__global__ __launch_bounds__(256, 3)
void gemm_bt(const unsigned short* __restrict__ A,
             const unsigned short* __restrict__ Bt,
             OutT* __restrict__ C,
             const float* __restrict__ bias,
             int M, int N, int K, int n_tiles, int mt_per_xcd) {
  __shared__ unsigned short Ash[128 * 64];   // 16 KB
  __shared__ unsigned short Bsh[128 * 64];   // 16 KB
  const int tid  = threadIdx.x;
  const int wv   = tid >> 6, lane = tid & 63;
  const int quad = lane >> 4, l15 = lane & 15;
  const int wr   = wv >> 1, wc = wv & 1;

  const int b = blockIdx.x;
  const int xcd = b & 7, local = b >> 3;
  const int mt = xcd * mt_per_xcd + local / n_tiles;
  const int nt = local % n_tiles;
  const int m0 = mt * 128, n0 = nt * 128;

  // staging: 1024 16B-groups per matrix; p in 0..3, lin = p*256+tid
  // LDS slot lin = (row = lin>>3, cg = lin&7); global group = cg ^ (row&7)
  const unsigned short* pA[4];
  const unsigned short* pB[4];
  #pragma unroll
  for (int p = 0; p < 4; ++p) {
    int lin = p * 256 + tid;
    int row = lin >> 3, g = (lin & 7) ^ (row & 7);
    pA[p] = &A[(size_t)(m0 + row) * K + g * 8];
    pB[p] = &Bt[(size_t)(n0 + row) * K + g * 8];
  }

  f32x4 acc[4][4];
  #pragma unroll
  for (int i = 0; i < 4; ++i)
    #pragma unroll
    for (int j = 0; j < 4; ++j)
      acc[i][j] = (f32x4){0.f, 0.f, 0.f, 0.f};

  for (int k0 = 0; k0 < K; k0 += 64) {
    #pragma unroll
    for (int p = 0; p < 4; ++p)
      async_copy16(pA[p] + k0, &Ash[(p * 256 + tid) * 8]);
    #pragma unroll
    for (int p = 0; p < 4; ++p)
      async_copy16(pB[p] + k0, &Bsh[(p * 256 + tid) * 8]);
    __syncthreads();
    #pragma unroll
    for (int ks = 0; ks < 2; ++ks) {
      const int swz = (((ks * 4 + quad) ^ (l15 & 7)) * 8);
      bf16x8 af[4], bfr[4];
      #pragma unroll
      for (int i = 0; i < 4; ++i)
        af[i] = lds_frag(&Ash[(wr * 64 + i * 16 + l15) * 64 + swz]);
      #pragma unroll
      for (int j = 0; j < 4; ++j)
        bfr[j] = lds_frag(&Bsh[(wc * 64 + j * 16 + l15) * 64 + swz]);
      #pragma unroll
      for (int i = 0; i < 4; ++i)
        #pragma unroll
        for (int j = 0; j < 4; ++j)
          acc[i][j] = __builtin_amdgcn_mfma_f32_16x16x32_bf16(af[i], bfr[j], acc[i][j], 0, 0, 0);
    }
    __syncthreads();
  }

  #pragma unroll
  for (int i = 0; i < 4; ++i) {
    #pragma unroll
    for (int j = 0; j < 4; ++j) {
      int col = n0 + wc * 64 + j * 16 + l15;
      float badd = (bias != nullptr) ? bias[col] : 0.f;
      #pragma unroll
      for (int r = 0; r < 4; ++r) {
        int row = m0 + wr * 64 + i * 16 + quad * 4 + r;
        if constexpr (sizeof(OutT) == 2)
          C[(size_t)row * N + col] = f2bf(acc[i][j][r] + badd);
        else
          C[(size_t)row * N + col] = acc[i][j][r] + badd;
      }
    }
  }
}

// Local attention: one block per (head, window). qkv: 16384 x 1536 bf16,
// out: 16384 x 512 bf16. WSZ=128, lookback window of 128 (zeros for w==0).
// mask: col <= row + 128. scale = 1/8.
__global__ __launch_bounds__(256, 2)
void attn_local(const unsigned short* __restrict__ qkv,
                unsigned short* __restrict__ out) {
  // Ksh: [ks(2)][j(256)][32] (64B rows -> b128 frags). Psh overlays Ksh.
  // VshT: V^T col-major [n(64)][k(256)], XOR swizzle: 16B-group g of row n at
  // slot g^(n&7) -> both staging stores and PV frag reads are conflict-optimal.
  __shared__ unsigned short Ksh[2 * 256 * 32];   // 32 KB
  __shared__ unsigned short VshT[64 * 256];      // 32 KB
  unsigned short* Psh = Ksh;

  const int tid  = threadIdx.x;
  const int wv   = tid >> 6, lane = tid & 63;
  const int quad = lane >> 4, l15 = lane & 15;
  const int h = blockIdx.x & 7, w = blockIdx.x >> 3;

  // stage K (k-tiled); rows j<128 of window 0 are zeros
  #pragma unroll
  for (int p = 0; p < 8; ++p) {
    int c = p * 256 + tid;                 // 2048 = 256 rows x 8 vec8-groups
    int j = c >> 3, sub = c & 7;
    u32x4 kvv = (u32x4){0, 0, 0, 0};
    if (!(w == 0 && j < 128)) {
      size_t base = (size_t)((w - 1) * 128 + j) * 1536 + h * 64 + sub * 8;
      kvv = *(const u32x4*)&qkv[base + 512];
    }
    *(u32x4*)&Ksh[(sub >> 2) * 8192 + j * 32 + (sub & 3) * 8] = kvv;
  }
  // stage V^T: thread (n = tid&63, kb4 = tid>>6) loads column n, 8 k's per iter
  {
    const int n = tid & 63, kb4 = tid >> 6;
    #pragma unroll
    for (int kk = 0; kk < 8; ++kk) {
      int kb = kk * 4 + kb4;               // group 0..31, k0 = kb*8
      unsigned short tmp[8];
      if (w == 0 && kb < 16) {
        #pragma unroll
        for (int j = 0; j < 8; ++j) tmp[j] = 0;
      } else {
        #pragma unroll
        for (int j = 0; j < 8; ++j)
          tmp[j] = qkv[(size_t)((w - 1) * 128 + kb * 8 + j) * 1536 + 1024 + h * 64 + n];
      }
      *(u32x4*)&VshT[n * 256 + ((kb ^ (n & 7)) * 8)] = *(u32x4*)tmp;
    }
  }
  __syncthreads();

  // Q fragments straight from global (A-operand: row l15, k = ks*32+quad*8..+7)
  bf16x8 qf[2][2];
  #pragma unroll
  for (int mt = 0; mt < 2; ++mt) {
    int tok = w * 128 + (wv * 2 + mt) * 16 + l15;
    #pragma unroll
    for (int ks = 0; ks < 2; ++ks)
      qf[mt][ks] = __builtin_bit_cast(
          bf16x8, *(const u32x4*)&qkv[(size_t)tok * 1536 + h * 64 + ks * 32 + quad * 8]);
  }

  // scores: wave wv owns rows [wv*32, wv*32+32) => m-tiles {2wv, 2wv+1}
  float s[2][16][4];
  #pragma unroll
  for (int nt = 0; nt < 16; ++nt) {
    bf16x8 kf0 = lds_frag(&Ksh[0    + (nt * 16 + l15) * 32 + quad * 8]);
    bf16x8 kf1 = lds_frag(&Ksh[8192 + (nt * 16 + l15) * 32 + quad * 8]);
    #pragma unroll
    for (int mt = 0; mt < 2; ++mt) {
      f32x4 a = (f32x4){0.f, 0.f, 0.f, 0.f};
      a = __builtin_amdgcn_mfma_f32_16x16x32_bf16(qf[mt][0], kf0, a, 0, 0, 0);
      a = __builtin_amdgcn_mfma_f32_16x16x32_bf16(qf[mt][1], kf1, a, 0, 0, 0);
      #pragma unroll
      for (int r = 0; r < 4; ++r) s[mt][nt][r] = a[r];
    }
  }

  // masked softmax in registers (row = mtile*16 + quad*4 + r, col = nt*16 + l15)
  #pragma unroll
  for (int mt = 0; mt < 2; ++mt) {
    int rowb = (wv * 2 + mt) * 16 + quad * 4;
    #pragma unroll
    for (int r = 0; r < 4; ++r) {
      int lim = rowb + r + 128;
      float mx = -3.0e38f;
      #pragma unroll
      for (int nt = 0; nt < 16; ++nt) {
        float v = ((nt * 16 + l15) <= lim) ? s[mt][nt][r] * 0.125f : -3.0e38f;
        s[mt][nt][r] = v;
        mx = fmaxf(mx, v);
      }
      mx = fmaxf(mx, __shfl_xor(mx, 1));
      mx = fmaxf(mx, __shfl_xor(mx, 2));
      mx = fmaxf(mx, __shfl_xor(mx, 4));
      mx = fmaxf(mx, __shfl_xor(mx, 8));
      float sum = 0.f;
      #pragma unroll
      for (int nt = 0; nt < 16; ++nt) {
        float p = __expf(s[mt][nt][r] - mx);   // masked -> exp(-huge) = 0
        s[mt][nt][r] = p;
        sum += p;
      }
      sum += __shfl_xor(sum, 1);
      sum += __shfl_xor(sum, 2);
      sum += __shfl_xor(sum, 4);
      sum += __shfl_xor(sum, 8);
      float inv = 1.f / sum;
      #pragma unroll
      for (int nt = 0; nt < 16; ++nt) s[mt][nt][r] *= inv;
    }
  }

  __syncthreads();   // all waves done reading Ksh -> safe to overlay P

  // PV: per m-tile, round-trip P through per-wave LDS region (C-layout -> A-layout)
  #pragma unroll
  for (int mt = 0; mt < 2; ++mt) {
    #pragma unroll
    for (int nt = 0; nt < 16; ++nt)
      #pragma unroll
      for (int r = 0; r < 4; ++r)
        Psh[wv * 4096 + (nt >> 1) * 512 + (quad * 4 + r) * 32 + (nt & 1) * 16 + l15] =
            f2bf(s[mt][nt][r]);
    __syncthreads();
    f32x4 o[4];
    #pragma unroll
    for (int n2 = 0; n2 < 4; ++n2) o[n2] = (f32x4){0.f, 0.f, 0.f, 0.f};
    #pragma unroll
    for (int ks = 0; ks < 8; ++ks) {
      bf16x8 pa = lds_frag(&Psh[wv * 4096 + ks * 512 + l15 * 32 + quad * 8]);
      #pragma unroll
      for (int n2 = 0; n2 < 4; ++n2) {
        bf16x8 vb = lds_frag(&VshT[(n2 * 16 + l15) * 256 + (((ks * 4 + quad) ^ (l15 & 7)) * 8)]);
        o[n2] = __builtin_amdgcn_mfma_f32_16x16x32_bf16(pa, vb, o[n2], 0, 0, 0);
      }
    }
    int tokb = w * 128 + (wv * 2 + mt) * 16 + quad * 4;
    #pragma unroll
    for (int n2 = 0; n2 < 4; ++n2)
      #pragma unroll
      for (int r = 0; r < 4; ++r)
        out[(size_t)(tokb + r) * 512 + h * 64 + n2 * 16 + l15] = f2bf(o[n2][r]);
    __syncthreads();
  }
}

extern "C" void kernel_launch(void* const* d_in, const int* in_sizes, int n_in,
                              void* d_out, int out_size, void* d_ws, size_t ws_size,
                              hipStream_t stream) {
  const float* x     = (const float*)d_in[0];  // 16384 x 1024 fp32
  const float* w_qkv = (const float*)d_in[1];  // 1024 x 1536 fp32
  const float* w_out = (const float*)d_in[2];  // 512 x 1024 fp32
  const float* b_out = (const float*)d_in[3];  // 1024 fp32
  float* out = (float*)d_out;                  // 16384 x 1024 fp32

  char* ws = (char*)d_ws;
  unsigned short* xb    = (unsigned short*)ws;                     // 16384x1024 bf16 (32 MB)
  unsigned short* wqkvT = (unsigned short*)(ws + 33554432);        // 1536x1024 (3 MB)
  unsigned short* woutT = (unsigned short*)(ws + 36700160);        // 1024x512  (1 MB)
  unsigned short* qkv   = (unsigned short*)(ws + 37748736);        // 16384x1536 (48 MB)
  unsigned short* attno = (unsigned short*)(ws + 88080384);        // 16384x512 (16 MB)

  cast_bf16_k<<<8192, 256, 0, stream>>>(x, xb, 16384 * 1024);
  transpose_cast_k<<<dim3(48, 32), 256, 0, stream>>>(w_qkv, wqkvT, 1024, 1536);
  transpose_cast_k<<<dim3(32, 16), 256, 0, stream>>>(w_out, woutT, 512, 1024);
  // QKV: 128 m-tiles x 12 n-tiles; 16 m-tiles per xcd
  gemm_bt<unsigned short><<<1536, 256, 0, stream>>>(
      xb, wqkvT, qkv, nullptr, 16384, 1536, 1024, 12, 16);
  attn_local<<<1024, 256, 0, stream>>>(qkv, attno);
  // out-proj: 128 m-tiles x 8 n-tiles; 16 m-tiles per xcd
  gemm_bt<float><<<1024, 256, 0, stream>>>(
      attno, woutT, out, b_out, 16384, 1024, 512, 8, 16);
}